// Round 2
// baseline (435.868 us; speedup 1.0000x reference)
//
#include <hip/hip_runtime.h>
#include <hip/hip_bf16.h>
#include <cstdint>

// LongcatFlashTopkRouter R6.
// classify = HS @ W^T (fp32 via split-bf16 3-product MFMA 32x32x16), then
// softmax -> +bias -> top-8 -> gather unbiased scores * 1.5.
// Outputs (flat f32): classify [16384*256] | weights [16384*8] | indices [16384*8]
//
// R6 changes vs R5 (428.5 us):
//  - In-chunk software pipeline: staging of chunk c+1 (split8 + ds_write into
//    buf^1) moved INTO the ks loop at ks=1,2 (legal: barrier at chunk top
//    guarantees all waves finished reading buf^1); c+2 A-global-loads issued at
//    ks=3 (ar free after staging; ~6 ks of MFMA to cover HBM latency). R5 had
//    this whole tail serialized after ks=7 (may-alias pins ds_writes below the
//    chunk's ds_reads), putting ~300+ cyc on the critical path per chunk.
//  - lgkmcnt(0) before barrier now waits on ds_writes issued ~6 ks ago (free).

typedef __attribute__((ext_vector_type(8))) short short8;    // 8 bf16 MFMA A/B frag
typedef __attribute__((ext_vector_type(16))) float f32x16;   // 32x32 MFMA C/D frag

#define T_TOK  16384
#define DIM    4096
#define NE     256
#define TOPK_N 8

__device__ __forceinline__ float bf2f_u(unsigned short h) {
  return __uint_as_float(((unsigned int)h) << 16);
}
// pack 2 floats -> 2 bf16 RNE in one u32 (f0 low, f1 high); v_cvt_pk_bf16_f32 on gfx950
__device__ __forceinline__ unsigned cvt_pk2(float f0, float f1) {
  __hip_bfloat162 h2 = __float22bfloat162_rn(float2{f0, f1});
  unsigned u;
  __builtin_memcpy(&u, &h2, 4);
  return u;
}
// split 8 floats -> hi uint4 + lo uint4 (Markidis residual, exact)
__device__ __forceinline__ void split8(const float* f, uint4& hv, uint4& lv) {
  unsigned h[4], l[4];
#pragma unroll
  for (int c = 0; c < 4; ++c) {
    float a = f[2 * c], b = f[2 * c + 1];
    h[c] = cvt_pk2(a, b);
    float ra = a - bf2f_u((unsigned short)(h[c] & 0xffffu));
    float rb = b - bf2f_u((unsigned short)(h[c] >> 16));
    l[c] = cvt_pk2(ra, rb);
  }
  hv = uint4{h[0], h[1], h[2], h[3]};
  lv = uint4{l[0], l[1], l[2], l[3]};
}

// ---- pack W fp32 -> fragment-major hi/lo bf16 for 32x32x16 B-frags ---------------
// Wp[((nt*256 + s)*64 + h*32 + col)*8 + j] = W[nt*32+col][s*16 + h*8 + j]
__global__ __launch_bounds__(256) void convert_w_kernel(
    const float* __restrict__ W,
    unsigned short* __restrict__ Whp,
    unsigned short* __restrict__ Wlp) {
  const int t = blockIdx.x * 256 + threadIdx.x;   // 131072 threads
  const int e = t >> 9, k8 = t & 511;
  const int nt = e >> 5, col = e & 31;
  const int s = k8 >> 1, h = k8 & 1;
  const float* src = W + (size_t)e * DIM + k8 * 8;
  float f[8];
  *(float4*)(f)     = *(const float4*)src;
  *(float4*)(f + 4) = *(const float4*)(src + 4);
  uint4 hv, lv;
  split8(f, hv, lv);
  const size_t dst = ((size_t)(nt * 256 + s) * 64 + h * 32 + col) * 8;
  *(uint4*)(Whp + dst) = hv;
  *(uint4*)(Wlp + dst) = lv;
}

// ---- GEMM ------------------------------------------------------------------------
__device__ __forceinline__ f32x16 mfma32(short8 a, short8 b, f32x16 c) {
  return __builtin_amdgcn_mfma_f32_32x32x16_bf16(a, b, c, 0, 0, 0);
}

template <bool ATOMIC>
__global__ __launch_bounds__(256, 2) void gemm_router(
    const float* __restrict__ A,
    const unsigned short* __restrict__ Whp,
    const unsigned short* __restrict__ Wlp,
    float* C0,       // kh==0 target (classify); atomic target if ATOMIC
    float* C1) {     // kh==1 target (partial in ws); unused if ATOMIC
  // [buf][hilo][mt][ks(8)][lane][8] = 64 KB; frag read/write contiguous per wave
  __shared__ __align__(16) unsigned short Ash[2][2][2][8][64][8];

  const int tid  = threadIdx.x;
  const int w    = tid >> 6, l = tid & 63;
  const int band = blockIdx.x & 255;
  const int kh   = blockIdx.x >> 8;            // k-half 0..1
  const size_t kbase = (size_t)kh * 2048;
  float* C = (ATOMIC || kh == 0) ? C0 : C1;

  // staging: thread covers row = tid>>2, k-window (tid&3)*32 .. +32 (2 ks steps)
  const int srow = tid >> 2, kg = tid & 3;
  const int smt = srow >> 5, sr = srow & 31;
  const float* ap = A + (size_t)(band * 64 + srow) * DIM + kbase + kg * 32;

  // B packed pointers: wave w owns nt = 2w, 2w+1; k-step offset kh*128
  const unsigned short* ph0 = Whp + ((size_t)(2 * w)     * 256 + kh * 128) * 512 + (size_t)l * 8;
  const unsigned short* pl0 = Wlp + ((size_t)(2 * w)     * 256 + kh * 128) * 512 + (size_t)l * 8;
  const unsigned short* ph1 = Whp + ((size_t)(2 * w + 1) * 256 + kh * 128) * 512 + (size_t)l * 8;
  const unsigned short* pl1 = Wlp + ((size_t)(2 * w + 1) * 256 + kh * 128) * 512 + (size_t)l * 8;

  f32x16 acc00 = {}, acc01 = {}, acc10 = {}, acc11 = {};
  float ar[32];

  // prologue: chunk 0 -> LDS buf0; chunk 1 -> regs; B depth-2 prefetch
#pragma unroll
  for (int i = 0; i < 8; ++i)
    *(float4*)(ar + i * 4) = *(const float4*)(ap + i * 4);
  {
#pragma unroll
    for (int sub = 0; sub < 2; ++sub) {
      uint4 hv0, lv0, hv1, lv1;
      split8(ar + sub * 16,     hv0, lv0);
      split8(ar + sub * 16 + 8, hv1, lv1);
      const int ks = kg * 2 + sub;
      *(uint4*)&Ash[0][0][smt][ks][ 0 + sr][0] = hv0;
      *(uint4*)&Ash[0][0][smt][ks][32 + sr][0] = hv1;
      *(uint4*)&Ash[0][1][smt][ks][ 0 + sr][0] = lv0;
      *(uint4*)&Ash[0][1][smt][ks][32 + sr][0] = lv1;
    }
  }
#pragma unroll
  for (int i = 0; i < 8; ++i)
    *(float4*)(ar + i * 4) = *(const float4*)(ap + 128 + i * 4);

  short8 b[2][4];
  b[0][0] = *(const short8*)(ph0);
  b[0][1] = *(const short8*)(pl0);
  b[0][2] = *(const short8*)(ph1);
  b[0][3] = *(const short8*)(pl1);
  b[1][0] = *(const short8*)(ph0 + 512);
  b[1][1] = *(const short8*)(pl0 + 512);
  b[1][2] = *(const short8*)(ph1 + 512);
  b[1][3] = *(const short8*)(pl1 + 512);

  for (int c = 0; c < 16; ++c) {
    const int buf = c & 1;
    // T4: cross-wave hazard is LDS-only. Drain lgkm (my staging ds_writes,
    // issued ~6 ks ago -> near-free), raw barrier, NO vmcnt drain.
    asm volatile("s_waitcnt lgkmcnt(0)" ::: "memory");
    __builtin_amdgcn_s_barrier();
    asm volatile("" ::: "memory");   // no hoisting of buf reads above barrier

#pragma unroll
    for (int ks = 0; ks < 8; ++ks) {
      const int gs = c * 8 + ks;
      short8 B0h = b[gs & 1][0], B0l = b[gs & 1][1];
      short8 B1h = b[gs & 1][2], B1l = b[gs & 1][3];
      const size_t gp = (size_t)((gs + 2 < 128) ? gs + 2 : gs) * 512;
      b[gs & 1][0] = *(const short8*)(ph0 + gp);
      b[gs & 1][1] = *(const short8*)(pl0 + gp);
      b[gs & 1][2] = *(const short8*)(ph1 + gp);
      b[gs & 1][3] = *(const short8*)(pl1 + gp);

      short8 a0h = *(const short8*)&Ash[buf][0][0][ks][l][0];
      short8 a0l = *(const short8*)&Ash[buf][1][0][ks][l][0];
      short8 a1h = *(const short8*)&Ash[buf][0][1][ks][l][0];
      short8 a1l = *(const short8*)&Ash[buf][1][1][ks][l][0];

      __builtin_amdgcn_s_setprio(1);
      acc00 = mfma32(a0h, B0h, acc00);  acc01 = mfma32(a0h, B1h, acc01);
      acc10 = mfma32(a1h, B0h, acc10);  acc11 = mfma32(a1h, B1h, acc11);
      acc00 = mfma32(a0l, B0h, acc00);  acc01 = mfma32(a0l, B1h, acc01);
      acc10 = mfma32(a1l, B0h, acc10);  acc11 = mfma32(a1l, B1h, acc11);
      acc00 = mfma32(a0h, B0l, acc00);  acc01 = mfma32(a0h, B1l, acc01);
      acc10 = mfma32(a1h, B0l, acc10);  acc11 = mfma32(a1h, B1l, acc11);
      __builtin_amdgcn_s_setprio(0);

      // In-chunk pipeline: stage chunk c+1 into buf^1 at ks=1,2 (all waves
      // finished reading buf^1 before this chunk's barrier); issue chunk c+2
      // global loads at ks=3 (ar consumed by staging; ~6 ks to cover latency).
      if (c < 15) {
        if (ks == 1 || ks == 2) {
          const int sub = ks - 1;
          uint4 hv0, lv0, hv1, lv1;
          split8(ar + sub * 16,     hv0, lv0);
          split8(ar + sub * 16 + 8, hv1, lv1);
          const int kss = kg * 2 + sub;
          *(uint4*)&Ash[buf ^ 1][0][smt][kss][ 0 + sr][0] = hv0;
          *(uint4*)&Ash[buf ^ 1][0][smt][kss][32 + sr][0] = hv1;
          *(uint4*)&Ash[buf ^ 1][1][smt][kss][ 0 + sr][0] = lv0;
          *(uint4*)&Ash[buf ^ 1][1][smt][kss][32 + sr][0] = lv1;
        }
        if (ks == 3 && c + 2 < 16) {
#pragma unroll
          for (int i = 0; i < 8; ++i)
            *(float4*)(ar + i * 4) = *(const float4*)(ap + (size_t)(c + 2) * 128 + i * 4);
        }
      }
    }
  }

  // epilogue: 32x32 C/D layout col=lane&31, row=(r&3)+8*(r>>2)+4*(lane>>5)
  const int rb = band * 64 + 4 * (l >> 5);
  const int cb = w * 64 + (l & 31);
#pragma unroll
  for (int r = 0; r < 16; ++r) {
    const int row = rb + (r & 3) + 8 * (r >> 2);
    if (ATOMIC) {
      unsafeAtomicAdd(&C[(size_t)row * NE + cb],             acc00[r]);
      unsafeAtomicAdd(&C[(size_t)row * NE + cb + 32],        acc01[r]);
      unsafeAtomicAdd(&C[(size_t)(row + 32) * NE + cb],      acc10[r]);
      unsafeAtomicAdd(&C[(size_t)(row + 32) * NE + cb + 32], acc11[r]);
    } else {
      C[(size_t)row * NE + cb]             = acc00[r];
      C[(size_t)row * NE + cb + 32]        = acc01[r];
      C[(size_t)(row + 32) * NE + cb]      = acc10[r];
      C[(size_t)(row + 32) * NE + cb + 32] = acc11[r];
    }
  }
}

// ---- softmax + biased top-8 + gather: one wave per token -------------------------
// FUSE: classify = Cp0 + Cp1 (k-half partials), written back; else Cp0 is final.
template <bool FUSE>
__global__ __launch_bounds__(256) void topk_kernel(
    const float* __restrict__ Cp0, const float* __restrict__ Cp1,
    const float* __restrict__ bias, float* __restrict__ classify,
    float* __restrict__ wOut, float* __restrict__ iOut) {
  const int wave = threadIdx.x >> 6;
  const int lane = threadIdx.x & 63;
  const int tok  = blockIdx.x * 4 + wave;

  float4 c4 = *(const float4*)(Cp0 + (size_t)tok * NE + lane * 4);
  if (FUSE) {
    float4 p4 = *(const float4*)(Cp1 + (size_t)tok * NE + lane * 4);
    c4.x += p4.x; c4.y += p4.y; c4.z += p4.z; c4.w += p4.w;
    *(float4*)(classify + (size_t)tok * NE + lane * 4) = c4;
  }
  float v[4] = {c4.x, c4.y, c4.z, c4.w};

  float mx = fmaxf(fmaxf(v[0], v[1]), fmaxf(v[2], v[3]));
#pragma unroll
  for (int off = 32; off >= 1; off >>= 1) mx = fmaxf(mx, __shfl_xor(mx, off));

  float e0 = __expf(v[0] - mx), e1 = __expf(v[1] - mx);
  float e2 = __expf(v[2] - mx), e3 = __expf(v[3] - mx);
  float sum = e0 + e1 + e2 + e3;
#pragma unroll
  for (int off = 32; off >= 1; off >>= 1) sum += __shfl_xor(sum, off);

  float sc0 = e0 / sum, sc1 = e1 / sum, sc2 = e2 / sum, sc3 = e3 / sum;
  float4 b4 = *(const float4*)(bias + lane * 4);
  float ch0 = sc0 + b4.x, ch1 = sc1 + b4.y, ch2 = sc2 + b4.z, ch3 = sc3 + b4.w;

#pragma unroll
  for (int t = 0; t < TOPK_N; ++t) {
    float bv = ch0; int bi = 0; float bs = sc0;
    if (ch1 > bv) { bv = ch1; bi = 1; bs = sc1; }
    if (ch2 > bv) { bv = ch2; bi = 2; bs = sc2; }
    if (ch3 > bv) { bv = ch3; bi = 3; bs = sc3; }
    int be = lane * 4 + bi;
#pragma unroll
    for (int off = 32; off >= 1; off >>= 1) {
      float ov = __shfl_xor(bv, off);
      int   oe = __shfl_xor(be, off);
      float os = __shfl_xor(bs, off);
      if (ov > bv || (ov == bv && oe < be)) { bv = ov; be = oe; bs = os; }
    }
    if (lane == 0) {
      wOut[tok * TOPK_N + t] = bs * 1.5f;
      iOut[tok * TOPK_N + t] = (float)be;
    }
    bool own = (be >> 2) == lane;
    int  lb  = be & 3;
    if (own && lb == 0) ch0 = -INFINITY;
    if (own && lb == 1) ch1 = -INFINITY;
    if (own && lb == 2) ch2 = -INFINITY;
    if (own && lb == 3) ch3 = -INFINITY;
  }
}

extern "C" void kernel_launch(void* const* d_in, const int* in_sizes, int n_in,
                              void* d_out, int out_size, void* d_ws, size_t ws_size,
                              hipStream_t stream) {
  const float* hs   = (const float*)d_in[0];   // [16384, 4096] f32
  const float* W    = (const float*)d_in[1];   // [256, 4096]   f32
  const float* bias = (const float*)d_in[2];   // [256]         f32

  float* out      = (float*)d_out;
  float* classify = out;                               // 16384*256
  float* wOut     = out + (size_t)T_TOK * NE;          // 16384*8
  float* iOut     = wOut + (size_t)T_TOK * TOPK_N;     // 16384*8

  unsigned short* Whp = (unsigned short*)d_ws;         // 2 MB packed hi
  unsigned short* Wlp = Whp + (size_t)NE * DIM;        // 2 MB packed lo

  const size_t wpack_bytes = (size_t)NE * DIM * 2 * sizeof(unsigned short); // 4 MB
  const size_t part_bytes  = (size_t)T_TOK * NE * sizeof(float);            // 16 MB
  float* p1 = (float*)((char*)d_ws + wpack_bytes);

  convert_w_kernel<<<(NE * DIM / 8) / 256, 256, 0, stream>>>(W, Whp, Wlp);

  if (ws_size >= wpack_bytes + part_bytes) {
    // atomic-free: kh=0 -> classify, kh=1 -> p1; topk fuses the add
    gemm_router<false><<<512, 256, 0, stream>>>(hs, Whp, Wlp, classify, p1);
    topk_kernel<true><<<T_TOK / 4, 256, 0, stream>>>(classify, p1, bias,
                                                     classify, wOut, iOut);
  } else {
    // fallback: atomic combine onto zeroed classify
    hipMemsetAsync(classify, 0, part_bytes, stream);
    gemm_router<true><<<512, 256, 0, stream>>>(hs, Whp, Wlp, classify, classify);
    topk_kernel<false><<<T_TOK / 4, 256, 0, stream>>>(classify, nullptr, bias,
                                                      classify, wOut, iOut);
  }
}

// Round 3
// 426.101 us; speedup vs baseline: 1.0229x; 1.0229x over previous
//
#include <hip/hip_runtime.h>
#include <hip/hip_bf16.h>
#include <cstdint>

// LongcatFlashTopkRouter R7.
// classify = HS @ W^T (fp32 via split-bf16 3-product MFMA 32x32x16), then
// softmax -> +bias -> top-8 -> gather unbiased scores * 1.5.
// Outputs (flat f32): classify [16384*256] | weights [16384*8] | indices [16384*8]
//
// R7 changes vs R6 (435.9 us) / R5 (428.5 us):
//  - REVERT R6's in-loop staging interleave (may-alias ds_writes inside the ks
//    loop blocked the compiler's own one-ks-ahead ds_read prefetch; +7 us).
//  - Occupancy 2 -> 4 waves/SIMD: 512-thread blocks (8 waves), each wave owns
//    ONE nt (2mt x 1nt, acc = 32 VGPR). Same grid 512, same 64KB LDS, same
//    M=64 x E=256 x K=2048 tile, identical HBM/L2/C traffic. VGPR ~105 < 128
//    => 16 waves/CU (launch_bounds(512,4)). Doubles latency hiding for the
//    per-ks ds_read_b128 and L2 B-load latencies (the 2.3x-over-floor gap).

typedef __attribute__((ext_vector_type(8))) short short8;    // 8 bf16 MFMA A/B frag
typedef __attribute__((ext_vector_type(16))) float f32x16;   // 32x32 MFMA C/D frag

#define T_TOK  16384
#define DIM    4096
#define NE     256
#define TOPK_N 8

__device__ __forceinline__ float bf2f_u(unsigned short h) {
  return __uint_as_float(((unsigned int)h) << 16);
}
// pack 2 floats -> 2 bf16 RNE in one u32 (f0 low, f1 high); v_cvt_pk_bf16_f32 on gfx950
__device__ __forceinline__ unsigned cvt_pk2(float f0, float f1) {
  __hip_bfloat162 h2 = __float22bfloat162_rn(float2{f0, f1});
  unsigned u;
  __builtin_memcpy(&u, &h2, 4);
  return u;
}
// split 8 floats -> hi uint4 + lo uint4 (Markidis residual, exact)
__device__ __forceinline__ void split8(const float* f, uint4& hv, uint4& lv) {
  unsigned h[4], l[4];
#pragma unroll
  for (int c = 0; c < 4; ++c) {
    float a = f[2 * c], b = f[2 * c + 1];
    h[c] = cvt_pk2(a, b);
    float ra = a - bf2f_u((unsigned short)(h[c] & 0xffffu));
    float rb = b - bf2f_u((unsigned short)(h[c] >> 16));
    l[c] = cvt_pk2(ra, rb);
  }
  hv = uint4{h[0], h[1], h[2], h[3]};
  lv = uint4{l[0], l[1], l[2], l[3]};
}

// ---- pack W fp32 -> fragment-major hi/lo bf16 for 32x32x16 B-frags ---------------
// Wp[((nt*256 + s)*64 + h*32 + col)*8 + j] = W[nt*32+col][s*16 + h*8 + j]
__global__ __launch_bounds__(256) void convert_w_kernel(
    const float* __restrict__ W,
    unsigned short* __restrict__ Whp,
    unsigned short* __restrict__ Wlp) {
  const int t = blockIdx.x * 256 + threadIdx.x;   // 131072 threads
  const int e = t >> 9, k8 = t & 511;
  const int nt = e >> 5, col = e & 31;
  const int s = k8 >> 1, h = k8 & 1;
  const float* src = W + (size_t)e * DIM + k8 * 8;
  float f[8];
  *(float4*)(f)     = *(const float4*)src;
  *(float4*)(f + 4) = *(const float4*)(src + 4);
  uint4 hv, lv;
  split8(f, hv, lv);
  const size_t dst = ((size_t)(nt * 256 + s) * 64 + h * 32 + col) * 8;
  *(uint4*)(Whp + dst) = hv;
  *(uint4*)(Wlp + dst) = lv;
}

// ---- GEMM ------------------------------------------------------------------------
__device__ __forceinline__ f32x16 mfma32(short8 a, short8 b, f32x16 c) {
  return __builtin_amdgcn_mfma_f32_32x32x16_bf16(a, b, c, 0, 0, 0);
}

template <bool ATOMIC>
__global__ __launch_bounds__(512, 4) void gemm_router(
    const float* __restrict__ A,
    const unsigned short* __restrict__ Whp,
    const unsigned short* __restrict__ Wlp,
    float* C0,       // kh==0 target (classify); atomic target if ATOMIC
    float* C1) {     // kh==1 target (partial in ws); unused if ATOMIC
  // [buf][hilo][mt][ks(8)][lane][8] = 64 KB; frag read/write contiguous per wave
  __shared__ __align__(16) unsigned short Ash[2][2][2][8][64][8];

  const int tid  = threadIdx.x;
  const int w    = tid >> 6, l = tid & 63;   // 8 waves; wave w owns nt = w
  const int band = blockIdx.x & 255;
  const int kh   = blockIdx.x >> 8;            // k-half 0..1
  const size_t kbase = (size_t)kh * 2048;
  float* C = (ATOMIC || kh == 0) ? C0 : C1;

  // staging: thread covers row = tid>>3, k-window (tid&7)*16 .. +16 (1 ks step)
  const int srow = tid >> 3, kg = tid & 7;
  const int smt = srow >> 5, sr = srow & 31;
  const float* ap = A + (size_t)(band * 64 + srow) * DIM + kbase + kg * 16;

  // B packed pointers: wave w owns nt = w; k-step offset kh*128
  const unsigned short* ph = Whp + ((size_t)w * 256 + kh * 128) * 512 + (size_t)l * 8;
  const unsigned short* pl = Wlp + ((size_t)w * 256 + kh * 128) * 512 + (size_t)l * 8;

  f32x16 acc0 = {}, acc1 = {};
  float ar[16];

  // prologue: chunk 0 -> LDS buf0; chunk 1 -> regs; B depth-2 prefetch
#pragma unroll
  for (int i = 0; i < 4; ++i)
    *(float4*)(ar + i * 4) = *(const float4*)(ap + i * 4);
  {
    uint4 hv0, lv0, hv1, lv1;
    split8(ar,     hv0, lv0);
    split8(ar + 8, hv1, lv1);
    *(uint4*)&Ash[0][0][smt][kg][ 0 + sr][0] = hv0;
    *(uint4*)&Ash[0][0][smt][kg][32 + sr][0] = hv1;
    *(uint4*)&Ash[0][1][smt][kg][ 0 + sr][0] = lv0;
    *(uint4*)&Ash[0][1][smt][kg][32 + sr][0] = lv1;
  }
#pragma unroll
  for (int i = 0; i < 4; ++i)
    *(float4*)(ar + i * 4) = *(const float4*)(ap + 128 + i * 4);

  short8 b[2][2];
  b[0][0] = *(const short8*)(ph);
  b[0][1] = *(const short8*)(pl);
  b[1][0] = *(const short8*)(ph + 512);
  b[1][1] = *(const short8*)(pl + 512);

  for (int c = 0; c < 16; ++c) {
    const int buf = c & 1;
    // T4: cross-wave hazard is LDS-only. Drain lgkm (my staging ds_writes),
    // raw barrier, NO vmcnt drain -> A/B prefetch stays in flight across it.
    asm volatile("s_waitcnt lgkmcnt(0)" ::: "memory");
    __builtin_amdgcn_s_barrier();
    asm volatile("" ::: "memory");   // no hoisting of buf reads above barrier

#pragma unroll
    for (int ks = 0; ks < 8; ++ks) {
      const int gs = c * 8 + ks;
      short8 Bh = b[gs & 1][0], Bl = b[gs & 1][1];
      const size_t gp = (size_t)((gs + 2 < 128) ? gs + 2 : gs) * 512;
      b[gs & 1][0] = *(const short8*)(ph + gp);
      b[gs & 1][1] = *(const short8*)(pl + gp);

      short8 a0h = *(const short8*)&Ash[buf][0][0][ks][l][0];
      short8 a0l = *(const short8*)&Ash[buf][1][0][ks][l][0];
      short8 a1h = *(const short8*)&Ash[buf][0][1][ks][l][0];
      short8 a1l = *(const short8*)&Ash[buf][1][1][ks][l][0];

      __builtin_amdgcn_s_setprio(1);
      acc0 = mfma32(a0h, Bh, acc0);  acc1 = mfma32(a1h, Bh, acc1);
      acc0 = mfma32(a0l, Bh, acc0);  acc1 = mfma32(a1l, Bh, acc1);
      acc0 = mfma32(a0h, Bl, acc0);  acc1 = mfma32(a1h, Bl, acc1);
      __builtin_amdgcn_s_setprio(0);
    }

    if (c < 15) {
      // stage chunk c+1 (regs landed a full chunk ago) into the other buffer
      {
        uint4 hv0, lv0, hv1, lv1;
        split8(ar,     hv0, lv0);
        split8(ar + 8, hv1, lv1);
        *(uint4*)&Ash[buf ^ 1][0][smt][kg][ 0 + sr][0] = hv0;
        *(uint4*)&Ash[buf ^ 1][0][smt][kg][32 + sr][0] = hv1;
        *(uint4*)&Ash[buf ^ 1][1][smt][kg][ 0 + sr][0] = lv0;
        *(uint4*)&Ash[buf ^ 1][1][smt][kg][32 + sr][0] = lv1;
      }
      // issue chunk c+2 loads: a full chunk of compute to land
      if (c + 2 < 16) {
#pragma unroll
        for (int i = 0; i < 4; ++i)
          *(float4*)(ar + i * 4) = *(const float4*)(ap + (size_t)(c + 2) * 128 + i * 4);
      }
    }
  }

  // epilogue: 32x32 C/D layout col=lane&31, row=(r&3)+8*(r>>2)+4*(lane>>5)
  const int rb = band * 64 + 4 * (l >> 5);
  const int cb = w * 32 + (l & 31);
#pragma unroll
  for (int r = 0; r < 16; ++r) {
    const int row = rb + (r & 3) + 8 * (r >> 2);
    if (ATOMIC) {
      unsafeAtomicAdd(&C[(size_t)row * NE + cb],        acc0[r]);
      unsafeAtomicAdd(&C[(size_t)(row + 32) * NE + cb], acc1[r]);
    } else {
      C[(size_t)row * NE + cb]        = acc0[r];
      C[(size_t)(row + 32) * NE + cb] = acc1[r];
    }
  }
}

// ---- softmax + biased top-8 + gather: one wave per token -------------------------
// FUSE: classify = Cp0 + Cp1 (k-half partials), written back; else Cp0 is final.
template <bool FUSE>
__global__ __launch_bounds__(256) void topk_kernel(
    const float* __restrict__ Cp0, const float* __restrict__ Cp1,
    const float* __restrict__ bias, float* __restrict__ classify,
    float* __restrict__ wOut, float* __restrict__ iOut) {
  const int wave = threadIdx.x >> 6;
  const int lane = threadIdx.x & 63;
  const int tok  = blockIdx.x * 4 + wave;

  float4 c4 = *(const float4*)(Cp0 + (size_t)tok * NE + lane * 4);
  if (FUSE) {
    float4 p4 = *(const float4*)(Cp1 + (size_t)tok * NE + lane * 4);
    c4.x += p4.x; c4.y += p4.y; c4.z += p4.z; c4.w += p4.w;
    *(float4*)(classify + (size_t)tok * NE + lane * 4) = c4;
  }
  float v[4] = {c4.x, c4.y, c4.z, c4.w};

  float mx = fmaxf(fmaxf(v[0], v[1]), fmaxf(v[2], v[3]));
#pragma unroll
  for (int off = 32; off >= 1; off >>= 1) mx = fmaxf(mx, __shfl_xor(mx, off));

  float e0 = __expf(v[0] - mx), e1 = __expf(v[1] - mx);
  float e2 = __expf(v[2] - mx), e3 = __expf(v[3] - mx);
  float sum = e0 + e1 + e2 + e3;
#pragma unroll
  for (int off = 32; off >= 1; off >>= 1) sum += __shfl_xor(sum, off);

  float sc0 = e0 / sum, sc1 = e1 / sum, sc2 = e2 / sum, sc3 = e3 / sum;
  float4 b4 = *(const float4*)(bias + lane * 4);
  float ch0 = sc0 + b4.x, ch1 = sc1 + b4.y, ch2 = sc2 + b4.z, ch3 = sc3 + b4.w;

#pragma unroll
  for (int t = 0; t < TOPK_N; ++t) {
    float bv = ch0; int bi = 0; float bs = sc0;
    if (ch1 > bv) { bv = ch1; bi = 1; bs = sc1; }
    if (ch2 > bv) { bv = ch2; bi = 2; bs = sc2; }
    if (ch3 > bv) { bv = ch3; bi = 3; bs = sc3; }
    int be = lane * 4 + bi;
#pragma unroll
    for (int off = 32; off >= 1; off >>= 1) {
      float ov = __shfl_xor(bv, off);
      int   oe = __shfl_xor(be, off);
      float os = __shfl_xor(bs, off);
      if (ov > bv || (ov == bv && oe < be)) { bv = ov; be = oe; bs = os; }
    }
    if (lane == 0) {
      wOut[tok * TOPK_N + t] = bs * 1.5f;
      iOut[tok * TOPK_N + t] = (float)be;
    }
    bool own = (be >> 2) == lane;
    int  lb  = be & 3;
    if (own && lb == 0) ch0 = -INFINITY;
    if (own && lb == 1) ch1 = -INFINITY;
    if (own && lb == 2) ch2 = -INFINITY;
    if (own && lb == 3) ch3 = -INFINITY;
  }
}

extern "C" void kernel_launch(void* const* d_in, const int* in_sizes, int n_in,
                              void* d_out, int out_size, void* d_ws, size_t ws_size,
                              hipStream_t stream) {
  const float* hs   = (const float*)d_in[0];   // [16384, 4096] f32
  const float* W    = (const float*)d_in[1];   // [256, 4096]   f32
  const float* bias = (const float*)d_in[2];   // [256]         f32

  float* out      = (float*)d_out;
  float* classify = out;                               // 16384*256
  float* wOut     = out + (size_t)T_TOK * NE;          // 16384*8
  float* iOut     = wOut + (size_t)T_TOK * TOPK_N;     // 16384*8

  unsigned short* Whp = (unsigned short*)d_ws;         // 2 MB packed hi
  unsigned short* Wlp = Whp + (size_t)NE * DIM;        // 2 MB packed lo

  const size_t wpack_bytes = (size_t)NE * DIM * 2 * sizeof(unsigned short); // 4 MB
  const size_t part_bytes  = (size_t)T_TOK * NE * sizeof(float);            // 16 MB
  float* p1 = (float*)((char*)d_ws + wpack_bytes);

  convert_w_kernel<<<(NE * DIM / 8) / 256, 256, 0, stream>>>(W, Whp, Wlp);

  if (ws_size >= wpack_bytes + part_bytes) {
    // atomic-free: kh=0 -> classify, kh=1 -> p1; topk fuses the add
    gemm_router<false><<<512, 512, 0, stream>>>(hs, Whp, Wlp, classify, p1);
    topk_kernel<true><<<T_TOK / 4, 256, 0, stream>>>(classify, p1, bias,
                                                     classify, wOut, iOut);
  } else {
    // fallback: atomic combine onto zeroed classify
    hipMemsetAsync(classify, 0, part_bytes, stream);
    gemm_router<true><<<512, 512, 0, stream>>>(hs, Whp, Wlp, classify, classify);
    topk_kernel<false><<<T_TOK / 4, 256, 0, stream>>>(classify, nullptr, bias,
                                                      classify, wOut, iOut);
  }
}